// Round 12
// baseline (88.438 us; speedup 1.0000x reference)
//
#include <hip/hip_runtime.h>
#include <cstddef>

#define NWALKS 16384
#define TLEN   20
#define HDIM   128
#define WPB    64     // 2 independent pipelines of 32 walks
#define NTHR   512    // 8 waves

typedef __attribute__((ext_vector_type(8))) _Float16 f16x8;
typedef __attribute__((ext_vector_type(4))) _Float16 f16x4;
typedef __attribute__((ext_vector_type(2))) __fp16   h16x2;   // cvt_pkrtz result type
typedef __attribute__((ext_vector_type(4))) float    f32x4;

union H4 { f16x4 v; struct { h16x2 lo, hi; } p; };

// ---------------------------------------------------------------------------
// fold: Wc16 = f16(scale_row * (W_ih @ W_f)), Whh16 = f16(scale_row * W_hh),
// b_c = W_ih@b_f + b_ih (unscaled; scaled at load in gru_kernel).
//   r,z rows (0..255):  * -log2(e)   -> sigmoid(v) = rcp(1 + exp2(acc))
//   n  rows (256..383): * +2*log2(e) -> tanh(v)    = 1 - 2*rcp(exp2(acc)+1)
// ---------------------------------------------------------------------------
__global__ void fold_kernel(const float* __restrict__ W_f, const float* __restrict__ b_f,
                            const float* __restrict__ W_ih, const float* __restrict__ W_hh,
                            const float* __restrict__ b_ih,
                            _Float16* __restrict__ Wc16, _Float16* __restrict__ Whh16,
                            float* __restrict__ b_c) {
  const int r = blockIdx.x;    // 0..383
  const int i = threadIdx.x;   // 0..127
  const float scale = (r < 256) ? -1.4426950408889634f : 2.8853900817779268f;
  const float* wih = W_ih + r * HDIM;
  float acc = 0.f;
  for (int h = 0; h < HDIM; ++h) acc = fmaf(wih[h], W_f[h * HDIM + i], acc);
  Wc16[r * HDIM + i]  = (_Float16)(acc * scale);
  Whh16[r * HDIM + i] = (_Float16)(W_hh[r * HDIM + i] * scale);
  if (i == 0) {
    float bb = b_ih[r];
    for (int h = 0; h < HDIM; ++h) bb = fmaf(wih[h], b_f[h], bb);
    b_c[r] = bb;
  }
}

// ---------------------------------------------------------------------------
// Fused GRU, f16 MFMA, DUAL-PIPELINE + WAVE ANTI-ALIGNMENT.
// Two independent 32-walk pipelines (A,B), phase-shifted half a step. Waves
// carry a "flavor" bit chosen so SIMD-co-resident waves execute the two
// per-wave-private tasks of each barrier interval in OPPOSITE order:
//   flavor0 half1: MFMA_A(k)        ; GATES_B(k-1)+XWRITE_B
//   flavor1 half1: GATES_B(k-1)+XWR ; MFMA_A(k)
// => one wave per SIMD feeds the matrix pipe while the sibling runs VALU
// (in-order issue made phase-aligned waves serialize pipes in rounds 4-11).
// flavor = (wv ^ (wv>>2)) & 1 anti-aligns under both i%4 and i/2 wave->SIMD
// maps. Dataflow identical to round 11 (all single-buffered tile writes are
// barrier-separated from reads in both flavors). Per-wave geometry verified
// rounds 5-11: wave wv owns gate columns [wv*16,wv*16+16); lane (g,l15):
// j = wv*16+4g+{0..3}, walk = mt*16+l15; weights 96 regs; biases via MFMA
// C-in; LDS XOR-swizzled (16B chunk ^= row&7); raw lgkm-only barriers.
// ---------------------------------------------------------------------------
__global__ __launch_bounds__(NTHR, 1)
void gru_kernel(const float* __restrict__ x, const int* __restrict__ walks,
                const _Float16* __restrict__ Wc16, const _Float16* __restrict__ Whh16,
                const float* __restrict__ b_c, const float* __restrict__ b_hh,
                float* __restrict__ out) {
  __shared__ _Float16 hbufA[32][HDIM];
  __shared__ _Float16 xbufA[32][HDIM];
  __shared__ _Float16 hbufB[32][HDIM];
  __shared__ _Float16 xbufB[32][HDIM];
  __shared__ int      nodesA[TLEN][32];
  __shared__ int      nodesB[TLEN][32];

  const int tid  = threadIdx.x;
  const int lane = tid & 63;
  const int wv   = tid >> 6;        // 0..7 : j-tile
  const int g    = lane >> 4;       // 0..3 : k-chunk / j-quad
  const int l15  = lane & 15;
  const int jw   = wv * 16 + l15;   // weight row for frag loads
  const int j0   = wv * 16 + 4 * g; // this lane's 4 j-columns
  const int walk0 = blockIdx.x * WPB;
  const int flavor = (wv ^ (wv >> 2)) & 1;   // anti-align SIMD siblings

  for (int idx = tid; idx < TLEN * 32; idx += NTHR) {
    nodesA[idx >> 5][idx & 31] = walks[(walk0 +      (idx & 31)) * TLEN + (idx >> 5)];
    nodesB[idx >> 5][idx & 31] = walks[(walk0 + 32 + (idx & 31)) * TLEN + (idx >> 5)];
  }
  for (int idx = tid; idx < 32 * HDIM; idx += NTHR) {
    hbufA[0][idx] = (_Float16)0.f;
    hbufB[0][idx] = (_Float16)0.f;
  }

  // ---- persistent weight fragments (A-operand), 96 VGPR ----
  f16x8 wrx[4], wrh[4], wzx[4], wzh[4], wnx[4], wnh[4];
#pragma unroll
  for (int kt = 0; kt < 4; ++kt) {
    const int koff = kt * 32 + g * 8;
    wrx[kt] = *(const f16x8*)(Wc16  + (size_t)(jw)       * HDIM + koff);
    wzx[kt] = *(const f16x8*)(Wc16  + (size_t)(128 + jw) * HDIM + koff);
    wnx[kt] = *(const f16x8*)(Wc16  + (size_t)(256 + jw) * HDIM + koff);
    wrh[kt] = *(const f16x8*)(Whh16 + (size_t)(jw)       * HDIM + koff);
    wzh[kt] = *(const f16x8*)(Whh16 + (size_t)(128 + jw) * HDIM + koff);
    wnh[kt] = *(const f16x8*)(Whh16 + (size_t)(256 + jw) * HDIM + koff);
  }
  // ---- biases (scaled), used as MFMA C-in on kt==0 ----
  const float NEG_L2E = -1.4426950408889634f;
  const float TWO_L2E =  2.8853900817779268f;
  const f32x4 br4  = NEG_L2E * (*(const f32x4*)&b_c[j0]       + *(const f32x4*)&b_hh[j0]);
  const f32x4 bz4  = NEG_L2E * (*(const f32x4*)&b_c[128 + j0] + *(const f32x4*)&b_hh[128 + j0]);
  const f32x4 bxn4 = TWO_L2E * (*(const f32x4*)&b_c[256 + j0]);
  const f32x4 bhn4 = TWO_L2E * (*(const f32x4*)&b_hh[256 + j0]);

  f32x4 hprevA[2], hprevB[2];
  hprevA[0] = 0.f; hprevA[1] = 0.f;
  hprevB[0] = 0.f; hprevB[1] = 0.f;

  // ---- swizzled LDS offsets (f16-element units) ----
  int voffs[4];
#pragma unroll
  for (int kt = 0; kt < 4; ++kt)
    voffs[kt] = l15 * HDIM + ((((kt * 4 + g) ^ (l15 & 7))) << 3);
  const int srow = tid >> 4;   // 0..31
  const int sc   = tid & 15;   // 8-float chunk
  const int xw   = srow * HDIM + ((sc ^ (srow & 7)) << 3);
  const int hw   = l15 * HDIM + (((2 * wv + (g >> 1)) ^ (l15 & 7)) << 3) + ((g & 1) << 2);

  // accumulators (live across halves)
  f32x4 arA[2], azA[2], anA[2], ah2A[2];
  f32x4 arB[2], azB[2], anB[2], ah2B[2];
  f32x4 GA0, GA1, GB0, GB1;   // gathered x rows in flight

  __syncthreads();   // nodes + zero h visible

  // ---- prologue: stage x_A[0], x_B[0] directly ----
  {
    const unsigned offA = ((unsigned)nodesA[0][srow] << 7) + sc * 8u;
    const unsigned offB = ((unsigned)nodesB[0][srow] << 7) + sc * 8u;
    const f32x4 a0 = *(const f32x4*)(x + offA);
    const f32x4 a1 = *(const f32x4*)(x + offA + 4);
    const f32x4 b0 = *(const f32x4*)(x + offB);
    const f32x4 b1 = *(const f32x4*)(x + offB + 4);
    H4 va, vb, wa, wb;
    va.p.lo = __builtin_amdgcn_cvt_pkrtz(a0.x, a0.y);
    va.p.hi = __builtin_amdgcn_cvt_pkrtz(a0.z, a0.w);
    vb.p.lo = __builtin_amdgcn_cvt_pkrtz(a1.x, a1.y);
    vb.p.hi = __builtin_amdgcn_cvt_pkrtz(a1.z, a1.w);
    wa.p.lo = __builtin_amdgcn_cvt_pkrtz(b0.x, b0.y);
    wa.p.hi = __builtin_amdgcn_cvt_pkrtz(b0.z, b0.w);
    wb.p.lo = __builtin_amdgcn_cvt_pkrtz(b1.x, b1.y);
    wb.p.hi = __builtin_amdgcn_cvt_pkrtz(b1.z, b1.w);
    *(f16x4*)(&xbufA[0][0] + xw)     = va.v;
    *(f16x4*)(&xbufA[0][0] + xw + 4) = vb.v;
    *(f16x4*)(&xbufB[0][0] + xw)     = wa.v;
    *(f16x4*)(&xbufB[0][0] + xw + 4) = wb.v;
  }
  __syncthreads();

#define RAWBAR()                                                                  \
  __builtin_amdgcn_sched_barrier(0);                                              \
  asm volatile("s_waitcnt lgkmcnt(0)" ::: "memory");                              \
  __builtin_amdgcn_s_barrier();                                                   \
  __builtin_amdgcn_sched_barrier(0);

#define GATHER(nodesP, T, G0, G1)                                                 \
  {                                                                               \
    const int tn = ((T) < TLEN) ? (T) : TLEN - 1;                                 \
    const unsigned o = ((unsigned)nodesP[tn][srow] << 7) + sc * 8u;               \
    G0 = *(const f32x4*)(x + o);                                                  \
    G1 = *(const f32x4*)(x + o + 4);                                              \
  }

#define MFMA_BLOCK(xbufP, hbufP, ar, az, an, ah2)                                 \
  {                                                                               \
    const _Float16* xb = &xbufP[0][0];                                            \
    const _Float16* hb = &hbufP[0][0];                                            \
    __builtin_amdgcn_s_setprio(1);                                                \
    _Pragma("unroll")                                                             \
    for (int kt = 0; kt < 4; ++kt) {                                              \
      const f16x8 ax0 = *(const f16x8*)(xb + voffs[kt]);                          \
      const f16x8 ax1 = *(const f16x8*)(xb + voffs[kt] + 16 * HDIM);              \
      const f16x8 ah0 = *(const f16x8*)(hb + voffs[kt]);                          \
      const f16x8 ah1 = *(const f16x8*)(hb + voffs[kt] + 16 * HDIM);              \
      ar[0]  = __builtin_amdgcn_mfma_f32_16x16x32_f16(wrx[kt], ax0, kt ? ar[0]  : br4,  0,0,0); \
      ar[1]  = __builtin_amdgcn_mfma_f32_16x16x32_f16(wrx[kt], ax1, kt ? ar[1]  : br4,  0,0,0); \
      ar[0]  = __builtin_amdgcn_mfma_f32_16x16x32_f16(wrh[kt], ah0, ar[0],  0,0,0); \
      ar[1]  = __builtin_amdgcn_mfma_f32_16x16x32_f16(wrh[kt], ah1, ar[1],  0,0,0); \
      az[0]  = __builtin_amdgcn_mfma_f32_16x16x32_f16(wzx[kt], ax0, kt ? az[0]  : bz4,  0,0,0); \
      az[1]  = __builtin_amdgcn_mfma_f32_16x16x32_f16(wzx[kt], ax1, kt ? az[1]  : bz4,  0,0,0); \
      az[0]  = __builtin_amdgcn_mfma_f32_16x16x32_f16(wzh[kt], ah0, az[0],  0,0,0); \
      az[1]  = __builtin_amdgcn_mfma_f32_16x16x32_f16(wzh[kt], ah1, az[1],  0,0,0); \
      an[0]  = __builtin_amdgcn_mfma_f32_16x16x32_f16(wnx[kt], ax0, kt ? an[0]  : bxn4, 0,0,0); \
      an[1]  = __builtin_amdgcn_mfma_f32_16x16x32_f16(wnx[kt], ax1, kt ? an[1]  : bxn4, 0,0,0); \
      ah2[0] = __builtin_amdgcn_mfma_f32_16x16x32_f16(wnh[kt], ah0, kt ? ah2[0] : bhn4, 0,0,0); \
      ah2[1] = __builtin_amdgcn_mfma_f32_16x16x32_f16(wnh[kt], ah1, kt ? ah2[1] : bhn4, 0,0,0); \
    }                                                                             \
    __builtin_amdgcn_s_setprio(0);                                                \
  }

#define GATES(ar, az, an, ah2, hprevP, hbufP)                                     \
  {                                                                               \
    _Pragma("unroll")                                                             \
    for (int mt = 0; mt < 2; ++mt) {                                              \
      f32x4 hn;                                                                   \
      _Pragma("unroll")                                                           \
      for (int r = 0; r < 4; ++r) {                                               \
        const float rv = __builtin_amdgcn_rcpf(1.f + __builtin_amdgcn_exp2f(ar[mt][r])); \
        const float zv = __builtin_amdgcn_rcpf(1.f + __builtin_amdgcn_exp2f(az[mt][r])); \
        const float en = __builtin_amdgcn_exp2f(fmaf(rv, ah2[mt][r], an[mt][r])); \
        const float nv = fmaf(-2.f, __builtin_amdgcn_rcpf(en + 1.f), 1.f);        \
        hn[r] = fmaf(zv, hprevP[mt][r] - nv, nv);                                 \
      }                                                                           \
      hprevP[mt] = hn;                                                            \
      H4 hp;                                                                      \
      hp.p.lo = __builtin_amdgcn_cvt_pkrtz(hn[0], hn[1]);                         \
      hp.p.hi = __builtin_amdgcn_cvt_pkrtz(hn[2], hn[3]);                         \
      *(f16x4*)(&hbufP[0][0] + hw + mt * 16 * HDIM) = hp.v;                       \
    }                                                                             \
  }

#define XWRITE(xbufP, G0, G1)                                                     \
  {                                                                               \
    H4 lo, hi;                                                                    \
    lo.p.lo = __builtin_amdgcn_cvt_pkrtz(G0.x, G0.y);                             \
    lo.p.hi = __builtin_amdgcn_cvt_pkrtz(G0.z, G0.w);                             \
    hi.p.lo = __builtin_amdgcn_cvt_pkrtz(G1.x, G1.y);                             \
    hi.p.hi = __builtin_amdgcn_cvt_pkrtz(G1.z, G1.w);                             \
    *(f16x4*)(&xbufP[0][0] + xw)     = lo.v;                                      \
    *(f16x4*)(&xbufP[0][0] + xw + 4) = hi.v;                                      \
  }

#pragma unroll 1
  for (int k = 0; k < TLEN; ++k) {
    // ---------- half1: {MFMA_A(k)} x {GATES_B(k-1)+XWRITE_B} anti-aligned ----------
    GATHER(nodesA, k + 1, GA0, GA1)
    if (flavor == 0) {
      MFMA_BLOCK(xbufA, hbufA, arA, azA, anA, ah2A)
      if (k > 0) {
        GATES(arB, azB, anB, ah2B, hprevB, hbufB)   // h_B[k] -> hbufB
        XWRITE(xbufB, GB0, GB1)                     // x_B[k] -> xbufB
      }
    } else {
      if (k > 0) {
        GATES(arB, azB, anB, ah2B, hprevB, hbufB)
        XWRITE(xbufB, GB0, GB1)
      }
      MFMA_BLOCK(xbufA, hbufA, arA, azA, anA, ah2A)
    }
    RAWBAR()
    // ---------- half2: {MFMA_B(k)} x {GATES_A(k)+XWRITE_A} anti-aligned ----------
    GATHER(nodesB, k + 1, GB0, GB1)
    if (flavor == 0) {
      MFMA_BLOCK(xbufB, hbufB, arB, azB, anB, ah2B)
      GATES(arA, azA, anA, ah2A, hprevA, hbufA)     // h_A[k+1] -> hbufA
      XWRITE(xbufA, GA0, GA1)                       // x_A[k+1] -> xbufA
    } else {
      GATES(arA, azA, anA, ah2A, hprevA, hbufA)
      XWRITE(xbufA, GA0, GA1)
      MFMA_BLOCK(xbufB, hbufB, arB, azB, anB, ah2B)
    }
    RAWBAR()
  }
  // ---------- epilogue: finish B's last step ----------
  GATES(arB, azB, anB, ah2B, hprevB, hbufB)

#undef RAWBAR
#undef GATHER
#undef MFMA_BLOCK
#undef GATES
#undef XWRITE

  // ---- final h: lane holds j0..j0+3 for walks (A: l15/16+l15, B: +32) ----
#pragma unroll
  for (int mt = 0; mt < 2; ++mt) {
    float4 oa = make_float4(hprevA[mt][0], hprevA[mt][1], hprevA[mt][2], hprevA[mt][3]);
    float4 ob = make_float4(hprevB[mt][0], hprevB[mt][1], hprevB[mt][2], hprevB[mt][3]);
    *(float4*)&out[(size_t)(walk0 +      mt * 16 + l15) * HDIM + j0] = oa;
    *(float4*)&out[(size_t)(walk0 + 32 + mt * 16 + l15) * HDIM + j0] = ob;
  }
}

extern "C" void kernel_launch(void* const* d_in, const int* in_sizes, int n_in,
                              void* d_out, int out_size, void* d_ws, size_t ws_size,
                              hipStream_t stream) {
  const float* x     = (const float*)d_in[0];
  const int*   walks = (const int*)  d_in[1];
  const float* W_f   = (const float*)d_in[2];
  const float* b_f   = (const float*)d_in[3];
  const float* W_ih  = (const float*)d_in[4];
  const float* W_hh  = (const float*)d_in[5];
  const float* b_ih  = (const float*)d_in[6];
  const float* b_hh  = (const float*)d_in[7];
  float* out = (float*)d_out;

  _Float16* Wc16  = (_Float16*)d_ws;                 // 384*128 f16
  _Float16* Whh16 = Wc16 + 384 * HDIM;               // 384*128 f16
  float*    b_c   = (float*)(Whh16 + 384 * HDIM);    // 384 f32

  fold_kernel<<<3 * HDIM, HDIM, 0, stream>>>(W_f, b_f, W_ih, W_hh, b_ih, Wc16, Whh16, b_c);
  gru_kernel<<<NWALKS / WPB, NTHR, 0, stream>>>(x, walks, Wc16, Whh16, b_c, b_hh, out);
}